// Round 6
// baseline (320.574 us; speedup 1.0000x reference)
//
#include <hip/hip_runtime.h>

typedef unsigned short u16;
typedef __attribute__((ext_vector_type(8))) short s16x8;   // 8 bf16 (4 VGPRs)
typedef __attribute__((ext_vector_type(4))) float f32x4;   // MFMA 16x16 accumulator
typedef __attribute__((ext_vector_type(16))) float f32x16; // MFMA 32x32 accumulator

#define MFMA(a, b, c) __builtin_amdgcn_mfma_f32_16x16x32_bf16((a), (b), (c), 0, 0, 0)
#define MFMA32(a, b, c) __builtin_amdgcn_mfma_f32_32x32x16_bf16((a), (b), (c), 0, 0, 0)

// async global->LDS, 16B per lane; LDS dest must be wave-uniform base + lane*16
#define LDS16(gp, lp)                                                          \
  __builtin_amdgcn_global_load_lds(                                            \
      (__attribute__((address_space(1))) void*)(gp),                           \
      (__attribute__((address_space(3))) void*)(lp), 16, 0, 0)

#define WAITVM(n) asm volatile("s_waitcnt vmcnt(" #n ")" ::: "memory")

#if __has_builtin(__builtin_amdgcn_exp2f)
#define EXP2F(x) __builtin_amdgcn_exp2f(x)
#else
#define EXP2F(x) exp2f(x)
#endif
#if __has_builtin(__builtin_amdgcn_rcpf)
#define RCPF(x) __builtin_amdgcn_rcpf(x)
#else
#define RCPF(x) (1.0f / (x))
#endif

__device__ __forceinline__ u16 f2bf(float f) {
  unsigned u = __float_as_uint(f);
  u += 0x7fffu + ((u >> 16) & 1u);   // round-to-nearest-even
  return (u16)(u >> 16);
}

// pack two f32 -> 2x bf16 in one VGPR (lo = a, hi = b), RNE
__device__ __forceinline__ int cvtpk(float a, float b) {
  int r;
  asm("v_cvt_pk_bf16_f32 %0, %1, %2" : "=v"(r) : "v"(a), "v"(b));
  return r;
}

// ---------------------------------------------------------------- cast x -> bf16
__global__ void cast_x_kernel(const float* __restrict__ in, u16* __restrict__ out) {
  const int idx = (blockIdx.x * 256 + threadIdx.x) * 4;
  const float4 v = *(const float4*)(in + idx);
  ushort4 o;
  o.x = f2bf(v.x); o.y = f2bf(v.y); o.z = f2bf(v.z); o.w = f2bf(v.w);
  *(ushort4*)(out + idx) = o;
}

// ------------------------------------------- transpose+cast: [Kd][Nd] f32 -> [Nd][Kd] bf16
__global__ void transpose_cast(const float* __restrict__ in, u16* __restrict__ out,
                               int Kd, int Nd) {
  __shared__ float t[64][65];
  const int tid = threadIdx.x;
  const int nb = blockIdx.x * 64, kb = blockIdx.y * 64;
#pragma unroll
  for (int it = 0; it < 4; it++) {
    const int flat = it * 1024 + tid * 4;
    const int rr = flat >> 6, cc = flat & 63;
    const float4 v = *(const float4*)(in + (size_t)(kb + rr) * Nd + nb + cc);
    t[rr][cc] = v.x; t[rr][cc + 1] = v.y; t[rr][cc + 2] = v.z; t[rr][cc + 3] = v.w;
  }
  __syncthreads();
#pragma unroll
  for (int it = 0; it < 4; it++) {
    const int flat = it * 1024 + tid * 4;
    const int rn = flat >> 6, ck = flat & 63;
    ushort4 o;
    o.x = f2bf(t[ck][rn]);     o.y = f2bf(t[ck + 1][rn]);
    o.z = f2bf(t[ck + 2][rn]); o.w = f2bf(t[ck + 3][rn]);
    *(ushort4*)(out + (size_t)(nb + rn) * Kd + kb + ck) = o;
  }
}

// ---------------------------------------------------------------- 256x128 bf16 GEMM
// C = A[M][1024] * Bt[N][1024]^T, K = 1024, NKT = 32 K-tiles of 32.
// 512 threads = 8 waves (4M x 2N), per-wave 64x64 C-tile, 4x4 MFMA 16x16x32.
// 4 LDS pipeline buffers (96 KB); stage tile kt+3 after iter-kt barrier
// (its target buffer was last read in iter kt-1, whose reads complete before
// this barrier). One raw s_barrier + counted vmcnt(6) per K-tile; tail peeled.
// LDS chunk-major: slot n holds global (row = n&(R-1), kchunk = n>>log2R)
// -> frag reads are 256B-contiguous per 16 lanes = bank-conflict-free.
// EPI=0: scatter qkv (bf16, V transposed). EPI=1: fp32 C out.
template <int EPI>
__global__ __launch_bounds__(512, 2)
void gemm256(const u16* __restrict__ A, const u16* __restrict__ Bt,
             float* __restrict__ Cout, int Ndim,
             u16* __restrict__ qp, u16* __restrict__ kp, u16* __restrict__ vp) {
  __shared__ alignas(16) u16 L[4 * 12288];   // 4 x (A 8192 + B 4096) u16 = 96 KB
  const int tid = threadIdx.x;
  const int lane = tid & 63, wid = tid >> 6;
  const int r = lane & 15, qq = lane >> 4;
  const int wr = wid >> 1, wc = wid & 1;     // wave tile: rows wr*64, cols wc*64
  const int gx = gridDim.x;
  const int nwg = gx * gridDim.y;
  const int bid = blockIdx.x + gx * blockIdx.y;
  const int swz = (bid & 7) * (nwg >> 3) + (bid >> 3);   // bijective (nwg%8==0)
  const int tn = (swz % gx) * 128, tm = (swz / gx) * 256;

  f32x4 acc[4][4];
#pragma unroll
  for (int i = 0; i < 4; i++)
#pragma unroll
    for (int j = 0; j < 4; j++) acc[i][j] = (f32x4){0.f, 0.f, 0.f, 0.f};

  // staging: A chunk n in {tid, tid+512} -> (row n&255, kc n>>8); B chunk tid.
  const u16* gA = A + (size_t)(tm + (tid & 255)) * 1024 + (tid >> 8) * 8;
  const u16* gB = Bt + (size_t)(tn + (tid & 127)) * 1024 + (tid >> 7) * 8;
  const int la0 = tid * 8, la1 = (tid + 512) * 8, lb0 = 8192 + tid * 8;

#define GSTAGE(b, t)                                                \
  do {                                                              \
    const u16* ga_ = gA + (t) * 32;                                 \
    u16* lp_ = L + (b) * 12288;                                     \
    LDS16(ga_, lp_ + la0);                                          \
    LDS16(ga_ + 16, lp_ + la1);                                     \
    LDS16(gB + (t) * 32, lp_ + lb0);                                \
  } while (0)

  // frag read offsets (chunk-major, conflict-free)
  const int arow = wr * 64 + r, brow = wc * 64 + r;
  const int aoff = qq * 2048 + arow * 8;          // + fm*128
  const int boff = 8192 + qq * 1024 + brow * 8;   // + fn*128

#define GCOMPUTE(b)                                                 \
  do {                                                              \
    const u16* lp_ = L + (b) * 12288;                               \
    s16x8 af[4], bfv[4];                                            \
    _Pragma("unroll")                                               \
    for (int f = 0; f < 4; f++)                                     \
      af[f] = *(const s16x8*)(lp_ + aoff + f * 128);                \
    _Pragma("unroll")                                               \
    for (int f = 0; f < 4; f++)                                     \
      bfv[f] = *(const s16x8*)(lp_ + boff + f * 128);               \
    __builtin_amdgcn_s_setprio(1);                                  \
    _Pragma("unroll")                                               \
    for (int fm = 0; fm < 4; fm++)                                  \
      _Pragma("unroll")                                             \
      for (int fn = 0; fn < 4; fn++)                                \
        acc[fm][fn] = MFMA(af[fm], bfv[fn], acc[fm][fn]);           \
    __builtin_amdgcn_s_setprio(0);                                  \
  } while (0)

  GSTAGE(0, 0);
  GSTAGE(1, 1);
  GSTAGE(2, 2);
  for (int kt = 0; kt < 30; kt++) {
    WAITVM(6);                        // tile kt landed; kt+1, kt+2 in flight
    __builtin_amdgcn_s_barrier();
    if (kt < 29) GSTAGE((kt + 3) & 3, kt + 3);
    GCOMPUTE(kt & 3);
  }
  WAITVM(3);
  __builtin_amdgcn_s_barrier();
  GCOMPUTE(2);                        // kt = 30
  WAITVM(0);
  __builtin_amdgcn_s_barrier();
  GCOMPUTE(3);                        // kt = 31
#undef GSTAGE
#undef GCOMPUTE

  // epilogue: C/D layout col = lane&15 (=r), row = qq*4 + j2
  if (EPI == 0) {
#pragma unroll
    for (int fm = 0; fm < 4; fm++) {
#pragma unroll
      for (int j2 = 0; j2 < 4; j2++) {
        const int mm = tm + wr * 64 + fm * 16 + qq * 4 + j2;
        const int bb = mm >> 11, tt = mm & 2047;
#pragma unroll
        for (int fn = 0; fn < 4; fn++) {
          const int n = tn + wc * 64 + fn * 16 + r;
          const u16 bv = f2bf(acc[fm][fn][j2]);
          const int which = n >> 10;
          const int hh = (n >> 6) & 15, dd = n & 63;
          const int bhh = bb * 16 + hh;
          if (which == 0)      qp[((size_t)bhh * 2048 + tt) * 64 + dd] = bv;
          else if (which == 1) kp[((size_t)bhh * 2048 + tt) * 64 + dd] = bv;
          else                 vp[((size_t)bhh * 64 + dd) * 2048 + tt] = bv;  // V transposed
        }
      }
    }
  } else {
#pragma unroll
    for (int fm = 0; fm < 4; fm++) {
#pragma unroll
      for (int j2 = 0; j2 < 4; j2++) {
        const int mm = tm + wr * 64 + fm * 16 + qq * 4 + j2;
#pragma unroll
        for (int fn = 0; fn < 4; fn++) {
          const int n = tn + wc * 64 + fn * 16 + r;
          Cout[(size_t)mm * Ndim + n] = acc[fm][fn][j2];
        }
      }
    }
  }
}

// ---------------------------------------------------------------- flash attention
// 4 waves x 32 q-rows (q-block 128). KVBLK=64, double-buffered swizzled LDS.
// Swapped QK^T: S^T = mfma(K, Q); swapped PV: y^T = mfma(V^T, P^T).
// Grid: x = bh (uniform work), y = q-tile, heavy tiles first (LPT scheduling).
__global__ __launch_bounds__(256, 2)
void attn_fwd(const u16* __restrict__ qg, const u16* __restrict__ kg,
              const u16* __restrict__ vtg, u16* __restrict__ yg) {
  __shared__ alignas(16) u16 Kl[2][64 * 64];
  __shared__ alignas(16) u16 Vl[2][64 * 64];
  const int tid = threadIdx.x;
  const int w = tid >> 6, lane = tid & 63;
  const int q5 = lane & 31, hi = lane >> 5;
  const int bh = blockIdx.x;                               // b*16 + h (uniform)
  const int qi = (int)(gridDim.y - 1 - blockIdx.y);        // heavy-first
  const int qb = qi * 128;
  const int qrow = qb + w * 32 + q5;
  const float C = 0.18033688011112042f;      // 0.125 * log2(e)

  // Q fragment (B operand of QK^T): lane holds Q[qrow][d], d = ks*16 + hi*8 + j
  const u16* qbase = qg + ((size_t)bh * 2048 + qrow) * 64;
  s16x8 qf[4];
#pragma unroll
  for (int ks = 0; ks < 4; ks++)
    qf[ks] = *(const s16x8*)(qbase + ks * 16 + hi * 8);

  // staging sources: chunk c -> row c>>3, LDS slot c&7 holds global chunk (c&7)^(row&7)
  const int c0 = tid, c1 = tid + 256;
  const int r0 = c0 >> 3, s0 = (c0 & 7) ^ (r0 & 7);
  const int r1 = c1 >> 3, s1 = (c1 & 7) ^ (r1 & 7);
  const u16* kga = kg + ((size_t)bh * 2048 + r0) * 64 + s0 * 8;
  const u16* kgb = kg + ((size_t)bh * 2048 + r1) * 64 + s1 * 8;
  const u16* vga = vtg + ((size_t)bh * 64 + r0) * 2048 + s0 * 8;
  const u16* vgb = vtg + ((size_t)bh * 64 + r1) * 2048 + s1 * 8;

  f32x16 ya, yb;
#pragma unroll
  for (int r = 0; r < 16; r++) { ya[r] = 0.f; yb[r] = 0.f; }
  float m_run = -3.0e38f, l_run = 0.f;

  const int nt = qb / 64 + 2;

#define STAGE(b, t)                                               \
  do {                                                            \
    LDS16(kga + (size_t)(t) * 4096, Kl[b] + c0 * 8);              \
    LDS16(kgb + (size_t)(t) * 4096, Kl[b] + c1 * 8);              \
    LDS16(vga + (size_t)(t) * 64,   Vl[b] + c0 * 8);              \
    LDS16(vgb + (size_t)(t) * 64,   Vl[b] + c1 * 8);              \
  } while (0)

  STAGE(0, 0);
  __syncthreads();

  for (int t = 0; t < nt; t++) {
    const int buf = t & 1;
    if (t + 1 < nt) STAGE(buf ^ 1, t + 1);
    const int kv0 = t * 64;
    const u16* Kb = Kl[buf];
    const u16* Vb = Vl[buf];

    if (kv0 <= qb + w * 32 + 31) {  // wave has live rows in this kv-tile
      // ---- QK^T (swapped): S^T[key][q], key subtiles kb0 = keys 0..31, kb1 = 32..63
      f32x16 sa, sb;
#pragma unroll
      for (int r = 0; r < 16; r++) { sa[r] = 0.f; sb[r] = 0.f; }
      __builtin_amdgcn_s_setprio(1);
#pragma unroll
      for (int ks = 0; ks < 4; ks++) {
        const int slot = ((ks * 2 + hi) ^ (lane & 7)) * 8;
        const s16x8 ka  = *(const s16x8*)(Kb + q5 * 64 + slot);
        const s16x8 kb2 = *(const s16x8*)(Kb + (32 + q5) * 64 + slot);
        sa = MFMA32(ka, qf[ks], sa);
        sb = MFMA32(kb2, qf[ks], sb);
      }
      __builtin_amdgcn_s_setprio(0);

      // ---- hoist V-fragment LDS reads: latency hides under softmax VALU
      s16x8 va[4], vb2[4];
#pragma unroll
      for (int ks4 = 0; ks4 < 4; ks4++) {
        const int sv = ((ks4 * 2 + hi) ^ (lane & 7)) * 8;
        va[ks4]  = *(const s16x8*)(Vb + q5 * 64 + sv);
        vb2[ks4] = *(const s16x8*)(Vb + (32 + q5) * 64 + sv);
      }

      // ---- causal mask (only diagonal tiles need it)
      if (kv0 + 63 > qb + w * 32) {
#pragma unroll
        for (int r = 0; r < 16; r++) {
          const int kl = kv0 + (r & 3) + 8 * (r >> 2) + 4 * hi;
          if (kl > qrow)      sa[r] = -3.0e38f;
          if (kl + 32 > qrow) sb[r] = -3.0e38f;
        }
      }

      // ---- online softmax (stats lane-local; merge lane pair l <-> l^32)
      float mx0 = -3.0e38f, mx1 = -3.0e38f, mx2 = -3.0e38f, mx3 = -3.0e38f;
#pragma unroll
      for (int r = 0; r < 16; r += 4) {
        mx0 = fmaxf(mx0, fmaxf(sa[r], sb[r]));
        mx1 = fmaxf(mx1, fmaxf(sa[r + 1], sb[r + 1]));
        mx2 = fmaxf(mx2, fmaxf(sa[r + 2], sb[r + 2]));
        mx3 = fmaxf(mx3, fmaxf(sa[r + 3], sb[r + 3]));
      }
      float mx = fmaxf(fmaxf(mx0, mx1), fmaxf(mx2, mx3));
      mx = fmaxf(mx, __shfl_xor(mx, 32));
      const float mxs = mx * C;

      // defer-max (T13): skip O-rescale while per-tile max growth <= 8 (P <= 2^8)
      if (!__all(mxs - m_run <= 8.0f)) {
        const float m2 = fmaxf(m_run, mxs);
        const float alpha = EXP2F(m_run - m2);
        m_run = m2;
        l_run *= alpha;
#pragma unroll
        for (int r = 0; r < 16; r++) { ya[r] *= alpha; yb[r] *= alpha; }
      }

      const float nm2 = -m_run;
      float ls0 = 0.f, ls1 = 0.f, ls2 = 0.f, ls3 = 0.f;
#pragma unroll
      for (int r = 0; r < 16; r += 4) {
        float p;
        p = EXP2F(fmaf(sa[r], C, nm2));     sa[r] = p;     ls0 += p;
        p = EXP2F(fmaf(sa[r + 1], C, nm2)); sa[r + 1] = p; ls1 += p;
        p = EXP2F(fmaf(sa[r + 2], C, nm2)); sa[r + 2] = p; ls2 += p;
        p = EXP2F(fmaf(sa[r + 3], C, nm2)); sa[r + 3] = p; ls3 += p;
        p = EXP2F(fmaf(sb[r], C, nm2));     sb[r] = p;     ls0 += p;
        p = EXP2F(fmaf(sb[r + 1], C, nm2)); sb[r + 1] = p; ls1 += p;
        p = EXP2F(fmaf(sb[r + 2], C, nm2)); sb[r + 2] = p; ls2 += p;
        p = EXP2F(fmaf(sb[r + 3], C, nm2)); sb[r + 3] = p; ls3 += p;
      }
      float ls = (ls0 + ls1) + (ls2 + ls3);
      ls += __shfl_xor(ls, 32);
      l_run += ls;

      // ---- P -> bf16 B-fragments (P^T as MFMA B operand), per 32-key subtile
      s16x8 bfrag[4];
#pragma unroll
      for (int kb = 0; kb < 2; kb++) {
        const f32x16* pv = kb ? &sb : &sa;
        int wv[8], xv[8];
#pragma unroll
        for (int i = 0; i < 8; i++) wv[i] = cvtpk((*pv)[2 * i], (*pv)[2 * i + 1]);
#pragma unroll
        for (int i = 0; i < 8; i++) xv[i] = __shfl_xor(wv[i], 32);
        union { int4 i4; s16x8 s8; } u0, u1;
        u0.i4 = hi ? make_int4(xv[2], xv[3], wv[2], wv[3])
                   : make_int4(wv[0], wv[1], xv[0], xv[1]);
        u1.i4 = hi ? make_int4(xv[6], xv[7], wv[6], wv[7])
                   : make_int4(wv[4], wv[5], xv[4], xv[5]);
        bfrag[kb * 2]     = u0.s8;
        bfrag[kb * 2 + 1] = u1.s8;
      }

      // ---- PV (swapped): y^T[d][q] += V^T[d][k] * P^T[k][q]
      __builtin_amdgcn_s_setprio(1);
#pragma unroll
      for (int ks4 = 0; ks4 < 4; ks4++) {
        ya = MFMA32(va[ks4], bfrag[ks4], ya);
        yb = MFMA32(vb2[ks4], bfrag[ks4], yb);
      }
      __builtin_amdgcn_s_setprio(0);
    }
    __syncthreads();
  }
#undef STAGE

  // ---- finalize: y[b][t][h*64+d] = y^T[d][q] / l  (all lane-local)
  const float linv = RCPF(l_run);
  const int b = bh >> 4, h = bh & 15;
  u16* yrow = yg + ((size_t)b * 2048 + qrow) * 1024 + h * 64;
#pragma unroll
  for (int dt = 0; dt < 2; dt++) {
    const f32x16* Y = dt ? &yb : &ya;
#pragma unroll
    for (int p2 = 0; p2 < 8; p2++) {
      const int pk = cvtpk((*Y)[2 * p2] * linv, (*Y)[2 * p2 + 1] * linv);
      const int d0 = dt * 32 + (p2 >> 1) * 8 + hi * 4 + (p2 & 1) * 2;
      *reinterpret_cast<int*>(yrow + d0) = pk;
    }
  }
}

// ---------------------------------------------------------------- launcher
extern "C" void kernel_launch(void* const* d_in, const int* in_sizes, int n_in,
                              void* d_out, int out_size, void* d_ws, size_t ws_size,
                              hipStream_t stream) {
  const float* x = (const float*)d_in[0];       // [4,2048,1024]
  const float* wqkv = (const float*)d_in[1];    // [1024,3072]
  const float* wproj = (const float*)d_in[2];   // [1024,1024]
  float* out = (float*)d_out;                   // [4,2048,1024] fp32

  char* ws = (char*)d_ws;
  u16* xb     = (u16*)(ws);                 // 16.78 MB  [8192][1024] bf16
  u16* wqkvT  = (u16*)(ws + 16777216);      //  6.29 MB  [3072][1024] bf16
  u16* wprojT = (u16*)(ws + 23068672);      //  2.10 MB  [1024][1024] bf16
  u16* qw     = (u16*)(ws + 25165824);      // 16.78 MB  [64][2048][64]
  u16* kw     = (u16*)(ws + 41943040);      // 16.78 MB  [64][2048][64]
  u16* vtw    = (u16*)(ws + 58720256);      // 16.78 MB  [64][64][2048]
  u16* yw     = (u16*)(ws + 75497472);      // 16.78 MB  [8192][1024]
  (void)in_sizes; (void)n_in; (void)out_size; (void)ws_size;

  cast_x_kernel<<<8192, 256, 0, stream>>>(x, xb);
  transpose_cast<<<dim3(48, 16), 256, 0, stream>>>(wqkv, wqkvT, 1024, 3072);
  transpose_cast<<<dim3(16, 16), 256, 0, stream>>>(wproj, wprojT, 1024, 1024);
  gemm256<0><<<dim3(24, 32), 512, 0, stream>>>(xb, wqkvT, nullptr, 3072, qw, kw, vtw);
  attn_fwd<<<dim3(64, 16), 256, 0, stream>>>(qw, kw, vtw, yw);
  gemm256<1><<<dim3(8, 32), 512, 0, stream>>>(yw, wprojT, out, 1024,
                                              nullptr, nullptr, nullptr);
}

// Round 7
// 313.996 us; speedup vs baseline: 1.0209x; 1.0209x over previous
//
#include <hip/hip_runtime.h>

typedef unsigned short u16;
typedef __attribute__((ext_vector_type(8))) short s16x8;   // 8 bf16 (4 VGPRs)
typedef __attribute__((ext_vector_type(4))) float f32x4;   // MFMA 16x16 accumulator
typedef __attribute__((ext_vector_type(16))) float f32x16; // MFMA 32x32 accumulator

#define MFMA(a, b, c) __builtin_amdgcn_mfma_f32_16x16x32_bf16((a), (b), (c), 0, 0, 0)
#define MFMA32(a, b, c) __builtin_amdgcn_mfma_f32_32x32x16_bf16((a), (b), (c), 0, 0, 0)

// async global->LDS, 16B per lane; LDS dest must be wave-uniform base + lane*16
#define LDS16(gp, lp)                                                          \
  __builtin_amdgcn_global_load_lds(                                            \
      (__attribute__((address_space(1))) void*)(gp),                           \
      (__attribute__((address_space(3))) void*)(lp), 16, 0, 0)

#define WAITVM(n) asm volatile("s_waitcnt vmcnt(" #n ")" ::: "memory")

#if __has_builtin(__builtin_amdgcn_exp2f)
#define EXP2F(x) __builtin_amdgcn_exp2f(x)
#else
#define EXP2F(x) exp2f(x)
#endif
#if __has_builtin(__builtin_amdgcn_rcpf)
#define RCPF(x) __builtin_amdgcn_rcpf(x)
#else
#define RCPF(x) (1.0f / (x))
#endif

__device__ __forceinline__ u16 f2bf(float f) {
  unsigned u = __float_as_uint(f);
  u += 0x7fffu + ((u >> 16) & 1u);   // round-to-nearest-even
  return (u16)(u >> 16);
}

// pack two f32 -> 2x bf16 in one VGPR (lo = a, hi = b), RNE
__device__ __forceinline__ int cvtpk(float a, float b) {
  int r;
  asm("v_cvt_pk_bf16_f32 %0, %1, %2" : "=v"(r) : "v"(a), "v"(b));
  return r;
}

// ---------------------------------------------------------------- cast x -> bf16
__global__ void cast_x_kernel(const float* __restrict__ in, u16* __restrict__ out) {
  const int idx = (blockIdx.x * 256 + threadIdx.x) * 4;
  const float4 v = *(const float4*)(in + idx);
  ushort4 o;
  o.x = f2bf(v.x); o.y = f2bf(v.y); o.z = f2bf(v.z); o.w = f2bf(v.w);
  *(ushort4*)(out + idx) = o;
}

// ------------------------------------------- transpose+cast: [Kd][Nd] f32 -> [Nd][Kd] bf16
__global__ void transpose_cast(const float* __restrict__ in, u16* __restrict__ out,
                               int Kd, int Nd) {
  __shared__ float t[64][65];
  const int tid = threadIdx.x;
  const int nb = blockIdx.x * 64, kb = blockIdx.y * 64;
#pragma unroll
  for (int it = 0; it < 4; it++) {
    const int flat = it * 1024 + tid * 4;
    const int rr = flat >> 6, cc = flat & 63;
    const float4 v = *(const float4*)(in + (size_t)(kb + rr) * Nd + nb + cc);
    t[rr][cc] = v.x; t[rr][cc + 1] = v.y; t[rr][cc + 2] = v.z; t[rr][cc + 3] = v.w;
  }
  __syncthreads();
#pragma unroll
  for (int it = 0; it < 4; it++) {
    const int flat = it * 1024 + tid * 4;
    const int rn = flat >> 6, ck = flat & 63;
    ushort4 o;
    o.x = f2bf(t[ck][rn]);     o.y = f2bf(t[ck + 1][rn]);
    o.z = f2bf(t[ck + 2][rn]); o.w = f2bf(t[ck + 3][rn]);
    *(ushort4*)(out + (size_t)(nb + rn) * Kd + kb + ck) = o;
  }
}

// ---------------------------------------------------------------- 256x128 bf16 GEMM
// C = A[M][1024] * Bt[N][1024]^T, 32 K-tiles of BK=32.
// 512 threads = 8 waves (4M x 2N), per-wave 64x64, 16 MFMA 16x16x32 per K-tile.
// 3-buffer LDS ring (72 KB -> 2 blocks/CU). Per phase (one K-tile):
//   { ds_read x8 | stage tile t+2 (3 gload_lds) | barrier |
//     setprio(1) 16 MFMA setprio(0) | WAITVM(3) | barrier }
// counted vmcnt: never 0 in the loop (tail peeled). Race-safety: stage(t+2)
// targets the buffer of tile t-1 (last read before phase t-1's barriers; its
// ds_reads drain via the MFMA-use lgkm wait); reads of tile t are covered by
// all-waves WAITVM + barrier at end of phase t-1.
// LDS chunk-major (proven 0 bank conflicts): A slot n=kc*256+row at n*8 u16;
// B slot n=kc*128+col at 8192+n*8.  EPI=0: scatter qkv. EPI=1: fp32 C out.
template <int EPI>
__global__ __launch_bounds__(512, 4)
void gemmp(const u16* __restrict__ A, const u16* __restrict__ Bt,
           float* __restrict__ Cout, int Ndim,
           u16* __restrict__ qp, u16* __restrict__ kp, u16* __restrict__ vp) {
  __shared__ alignas(16) u16 L[3 * 12288];   // 3 x (A 16KB + B 8KB) = 72 KB
  const int tid = threadIdx.x;
  const int lane = tid & 63;
  const int wid = tid >> 6;
  const int r = lane & 15, qq = lane >> 4;
  const int wm = wid >> 1, wn = wid & 1;     // wave tile: rows wm*64, cols wn*64
  const int gx = gridDim.x;
  const int nwg = gx * gridDim.y;
  const int bid = blockIdx.x + gx * blockIdx.y;
  const int swz = (bid & 7) * (nwg >> 3) + (bid >> 3);   // bijective (nwg%8==0)
  const int tn = (swz % gx) * 128, tm = (swz / gx) * 256;

  f32x4 acc[4][4];
#pragma unroll
  for (int i = 0; i < 4; i++)
#pragma unroll
    for (int j = 0; j < 4; j++) acc[i][j] = (f32x4){0.f, 0.f, 0.f, 0.f};

  // staging: A chunks {tid, tid+512} -> (row=tid&255, kc=tid>>8 and +2); B chunk tid.
  const u16* gA = A + (size_t)(tm + (tid & 255)) * 1024 + (tid >> 8) * 8;
  const u16* gB = Bt + (size_t)(tn + (tid & 127)) * 1024 + (tid >> 7) * 8;
  const int la0 = tid * 8, la1 = tid * 8 + 4096, lb0 = 8192 + tid * 8;

#define GSTAGE(bb, t)                                               \
  do {                                                              \
    const u16* sa_ = gA + (size_t)(t) * 32;                         \
    u16* lp_ = L + (bb);                                            \
    LDS16(sa_, lp_ + la0);                                          \
    LDS16(sa_ + 16, lp_ + la1);                                     \
    LDS16(gB + (size_t)(t) * 32, lp_ + lb0);                        \
  } while (0)

  // frag read offsets (chunk-major, quarter-wave contiguous => conflict-free)
  const int aoff = qq * 2048 + (wm * 64 + r) * 8;          // + fm*128
  const int boff = 8192 + qq * 1024 + (wn * 64 + r) * 8;   // + fn*128

#define GPHASE(t, DO_STAGE, LAST)                                   \
  do {                                                              \
    const int bb_ = ((t) % 3) * 12288;                              \
    s16x8 af[4], bfv[4];                                            \
    _Pragma("unroll")                                               \
    for (int f = 0; f < 4; f++)                                     \
      af[f] = *(const s16x8*)(L + bb_ + aoff + f * 128);            \
    _Pragma("unroll")                                               \
    for (int f = 0; f < 4; f++)                                     \
      bfv[f] = *(const s16x8*)(L + bb_ + boff + f * 128);           \
    if (DO_STAGE) GSTAGE((((t) + 2) % 3) * 12288, (t) + 2);         \
    __builtin_amdgcn_s_barrier();                                   \
    __builtin_amdgcn_s_setprio(1);                                  \
    _Pragma("unroll")                                               \
    for (int fm = 0; fm < 4; fm++)                                  \
      _Pragma("unroll")                                             \
      for (int fn = 0; fn < 4; fn++)                                \
        acc[fm][fn] = MFMA(af[fm], bfv[fn], acc[fm][fn]);           \
    __builtin_amdgcn_s_setprio(0);                                  \
    if (!(LAST)) __builtin_amdgcn_s_barrier();                      \
  } while (0)

  GSTAGE(0, 0);
  GSTAGE(12288, 1);
  WAITVM(3);                      // tile 0 landed (tile 1 in flight)
  __builtin_amdgcn_s_barrier();
  for (int t = 0; t < 30; t++) {
    // phase t: compute tile t, stage tile t+2, then ensure t+1 landed
    const int bb_ = (t % 3) * 12288;
    s16x8 af[4], bfv[4];
#pragma unroll
    for (int f = 0; f < 4; f++)
      af[f] = *(const s16x8*)(L + bb_ + aoff + f * 128);
#pragma unroll
    for (int f = 0; f < 4; f++)
      bfv[f] = *(const s16x8*)(L + bb_ + boff + f * 128);
    GSTAGE(((t + 2) % 3) * 12288, t + 2);
    __builtin_amdgcn_s_barrier();
    __builtin_amdgcn_s_setprio(1);
#pragma unroll
    for (int fm = 0; fm < 4; fm++)
#pragma unroll
      for (int fn = 0; fn < 4; fn++)
        acc[fm][fn] = MFMA(af[fm], bfv[fn], acc[fm][fn]);
    __builtin_amdgcn_s_setprio(0);
    if (t < 29) WAITVM(3); else WAITVM(0);   // cover tile t+1 for all waves
    __builtin_amdgcn_s_barrier();
  }
  GPHASE(30, 0, 0);               // no stage; WAIT not needed (31 landed) but
  GPHASE(31, 0, 1);               // barrier separates 30's reads from nothing
#undef GSTAGE
#undef GPHASE

  // epilogue: C/D layout col = lane&15 (=r), row = qq*4 + j2
  if (EPI == 0) {
#pragma unroll
    for (int fm = 0; fm < 4; fm++) {
#pragma unroll
      for (int j2 = 0; j2 < 4; j2++) {
        const int mm = tm + wm * 64 + fm * 16 + qq * 4 + j2;
        const int bb = mm >> 11, tt = mm & 2047;
#pragma unroll
        for (int fn = 0; fn < 4; fn++) {
          const int n = tn + wn * 64 + fn * 16 + r;
          const u16 bv = f2bf(acc[fm][fn][j2]);
          const int which = n >> 10;
          const int hh = (n >> 6) & 15, dd = n & 63;
          const int bhh = bb * 16 + hh;
          if (which == 0)      qp[((size_t)bhh * 2048 + tt) * 64 + dd] = bv;
          else if (which == 1) kp[((size_t)bhh * 2048 + tt) * 64 + dd] = bv;
          else                 vp[((size_t)bhh * 64 + dd) * 2048 + tt] = bv;  // V transposed
        }
      }
    }
  } else {
#pragma unroll
    for (int fm = 0; fm < 4; fm++) {
#pragma unroll
      for (int j2 = 0; j2 < 4; j2++) {
        const int mm = tm + wm * 64 + fm * 16 + qq * 4 + j2;
#pragma unroll
        for (int fn = 0; fn < 4; fn++) {
          const int n = tn + wn * 64 + fn * 16 + r;
          Cout[(size_t)mm * Ndim + n] = acc[fm][fn][j2];
        }
      }
    }
  }
}

// ---------------------------------------------------------------- flash attention
// 4 waves x 32 q-rows (q-block 128). KVBLK=64, double-buffered swizzled LDS.
// Swapped QK^T: S^T = mfma(K, Q); swapped PV: y^T = mfma(V^T, P^T).
// Grid: x = bh (uniform work), y = q-tile, heavy tiles first (LPT scheduling).
__global__ __launch_bounds__(256, 2)
void attn_fwd(const u16* __restrict__ qg, const u16* __restrict__ kg,
              const u16* __restrict__ vtg, u16* __restrict__ yg) {
  __shared__ alignas(16) u16 Kl[2][64 * 64];
  __shared__ alignas(16) u16 Vl[2][64 * 64];
  const int tid = threadIdx.x;
  const int w = tid >> 6, lane = tid & 63;
  const int q5 = lane & 31, hi = lane >> 5;
  const int bh = blockIdx.x;                               // b*16 + h (uniform)
  const int qi = (int)(gridDim.y - 1 - blockIdx.y);        // heavy-first
  const int qb = qi * 128;
  const int qrow = qb + w * 32 + q5;
  const float C = 0.18033688011112042f;      // 0.125 * log2(e)

  // Q fragment (B operand of QK^T): lane holds Q[qrow][d], d = ks*16 + hi*8 + j
  const u16* qbase = qg + ((size_t)bh * 2048 + qrow) * 64;
  s16x8 qf[4];
#pragma unroll
  for (int ks = 0; ks < 4; ks++)
    qf[ks] = *(const s16x8*)(qbase + ks * 16 + hi * 8);

  // staging sources: chunk c -> row c>>3, LDS slot c&7 holds global chunk (c&7)^(row&7)
  const int c0 = tid, c1 = tid + 256;
  const int r0 = c0 >> 3, s0 = (c0 & 7) ^ (r0 & 7);
  const int r1 = c1 >> 3, s1 = (c1 & 7) ^ (r1 & 7);
  const u16* kga = kg + ((size_t)bh * 2048 + r0) * 64 + s0 * 8;
  const u16* kgb = kg + ((size_t)bh * 2048 + r1) * 64 + s1 * 8;
  const u16* vga = vtg + ((size_t)bh * 64 + r0) * 2048 + s0 * 8;
  const u16* vgb = vtg + ((size_t)bh * 64 + r1) * 2048 + s1 * 8;

  f32x16 ya, yb;
#pragma unroll
  for (int r = 0; r < 16; r++) { ya[r] = 0.f; yb[r] = 0.f; }
  float m_run = -3.0e38f, l_run = 0.f;

  const int nt = qb / 64 + 2;

#define STAGE(b, t)                                               \
  do {                                                            \
    LDS16(kga + (size_t)(t) * 4096, Kl[b] + c0 * 8);              \
    LDS16(kgb + (size_t)(t) * 4096, Kl[b] + c1 * 8);              \
    LDS16(vga + (size_t)(t) * 64,   Vl[b] + c0 * 8);              \
    LDS16(vgb + (size_t)(t) * 64,   Vl[b] + c1 * 8);              \
  } while (0)

  STAGE(0, 0);
  __syncthreads();

  for (int t = 0; t < nt; t++) {
    const int buf = t & 1;
    if (t + 1 < nt) STAGE(buf ^ 1, t + 1);
    const int kv0 = t * 64;
    const u16* Kb = Kl[buf];
    const u16* Vb = Vl[buf];

    if (kv0 <= qb + w * 32 + 31) {  // wave has live rows in this kv-tile
      // ---- QK^T (swapped): S^T[key][q], key subtiles kb0 = keys 0..31, kb1 = 32..63
      f32x16 sa, sb;
#pragma unroll
      for (int r = 0; r < 16; r++) { sa[r] = 0.f; sb[r] = 0.f; }
      __builtin_amdgcn_s_setprio(1);
#pragma unroll
      for (int ks = 0; ks < 4; ks++) {
        const int slot = ((ks * 2 + hi) ^ (lane & 7)) * 8;
        const s16x8 ka  = *(const s16x8*)(Kb + q5 * 64 + slot);
        const s16x8 kb2 = *(const s16x8*)(Kb + (32 + q5) * 64 + slot);
        sa = MFMA32(ka, qf[ks], sa);
        sb = MFMA32(kb2, qf[ks], sb);
      }
      __builtin_amdgcn_s_setprio(0);

      // ---- hoist V-fragment LDS reads: latency hides under softmax VALU
      s16x8 va[4], vb2[4];
#pragma unroll
      for (int ks4 = 0; ks4 < 4; ks4++) {
        const int sv = ((ks4 * 2 + hi) ^ (lane & 7)) * 8;
        va[ks4]  = *(const s16x8*)(Vb + q5 * 64 + sv);
        vb2[ks4] = *(const s16x8*)(Vb + (32 + q5) * 64 + sv);
      }

      // ---- causal mask (only diagonal tiles need it)
      if (kv0 + 63 > qb + w * 32) {
#pragma unroll
        for (int r = 0; r < 16; r++) {
          const int kl = kv0 + (r & 3) + 8 * (r >> 2) + 4 * hi;
          if (kl > qrow)      sa[r] = -3.0e38f;
          if (kl + 32 > qrow) sb[r] = -3.0e38f;
        }
      }

      // ---- online softmax (stats lane-local; merge lane pair l <-> l^32)
      float mx0 = -3.0e38f, mx1 = -3.0e38f, mx2 = -3.0e38f, mx3 = -3.0e38f;
#pragma unroll
      for (int r = 0; r < 16; r += 4) {
        mx0 = fmaxf(mx0, fmaxf(sa[r], sb[r]));
        mx1 = fmaxf(mx1, fmaxf(sa[r + 1], sb[r + 1]));
        mx2 = fmaxf(mx2, fmaxf(sa[r + 2], sb[r + 2]));
        mx3 = fmaxf(mx3, fmaxf(sa[r + 3], sb[r + 3]));
      }
      float mx = fmaxf(fmaxf(mx0, mx1), fmaxf(mx2, mx3));
      mx = fmaxf(mx, __shfl_xor(mx, 32));
      const float mxs = mx * C;

      // defer-max (T13): skip O-rescale while per-tile max growth <= 8 (P <= 2^8)
      if (!__all(mxs - m_run <= 8.0f)) {
        const float m2 = fmaxf(m_run, mxs);
        const float alpha = EXP2F(m_run - m2);
        m_run = m2;
        l_run *= alpha;
#pragma unroll
        for (int r = 0; r < 16; r++) { ya[r] *= alpha; yb[r] *= alpha; }
      }

      const float nm2 = -m_run;
      float ls0 = 0.f, ls1 = 0.f, ls2 = 0.f, ls3 = 0.f;
#pragma unroll
      for (int r = 0; r < 16; r += 4) {
        float p;
        p = EXP2F(fmaf(sa[r], C, nm2));     sa[r] = p;     ls0 += p;
        p = EXP2F(fmaf(sa[r + 1], C, nm2)); sa[r + 1] = p; ls1 += p;
        p = EXP2F(fmaf(sa[r + 2], C, nm2)); sa[r + 2] = p; ls2 += p;
        p = EXP2F(fmaf(sa[r + 3], C, nm2)); sa[r + 3] = p; ls3 += p;
        p = EXP2F(fmaf(sb[r], C, nm2));     sb[r] = p;     ls0 += p;
        p = EXP2F(fmaf(sb[r + 1], C, nm2)); sb[r + 1] = p; ls1 += p;
        p = EXP2F(fmaf(sb[r + 2], C, nm2)); sb[r + 2] = p; ls2 += p;
        p = EXP2F(fmaf(sb[r + 3], C, nm2)); sb[r + 3] = p; ls3 += p;
      }
      float ls = (ls0 + ls1) + (ls2 + ls3);
      ls += __shfl_xor(ls, 32);
      l_run += ls;

      // ---- P -> bf16 B-fragments (P^T as MFMA B operand), per 32-key subtile
      s16x8 bfrag[4];
#pragma unroll
      for (int kb = 0; kb < 2; kb++) {
        const f32x16* pv = kb ? &sb : &sa;
        int wv[8], xv[8];
#pragma unroll
        for (int i = 0; i < 8; i++) wv[i] = cvtpk((*pv)[2 * i], (*pv)[2 * i + 1]);
#pragma unroll
        for (int i = 0; i < 8; i++) xv[i] = __shfl_xor(wv[i], 32);
        union { int4 i4; s16x8 s8; } u0, u1;
        u0.i4 = hi ? make_int4(xv[2], xv[3], wv[2], wv[3])
                   : make_int4(wv[0], wv[1], xv[0], xv[1]);
        u1.i4 = hi ? make_int4(xv[6], xv[7], wv[6], wv[7])
                   : make_int4(wv[4], wv[5], xv[4], xv[5]);
        bfrag[kb * 2]     = u0.s8;
        bfrag[kb * 2 + 1] = u1.s8;
      }

      // ---- PV (swapped): y^T[d][q] += V^T[d][k] * P^T[k][q]
      __builtin_amdgcn_s_setprio(1);
#pragma unroll
      for (int ks4 = 0; ks4 < 4; ks4++) {
        ya = MFMA32(va[ks4], bfrag[ks4], ya);
        yb = MFMA32(vb2[ks4], bfrag[ks4], yb);
      }
      __builtin_amdgcn_s_setprio(0);
    }
    __syncthreads();
  }
#undef STAGE

  // ---- finalize: y[b][t][h*64+d] = y^T[d][q] / l  (all lane-local)
  const float linv = RCPF(l_run);
  const int b = bh >> 4, h = bh & 15;
  u16* yrow = yg + ((size_t)b * 2048 + qrow) * 1024 + h * 64;
#pragma unroll
  for (int dt = 0; dt < 2; dt++) {
    const f32x16* Y = dt ? &yb : &ya;
#pragma unroll
    for (int p2 = 0; p2 < 8; p2++) {
      const int pk = cvtpk((*Y)[2 * p2] * linv, (*Y)[2 * p2 + 1] * linv);
      const int d0 = dt * 32 + (p2 >> 1) * 8 + hi * 4 + (p2 & 1) * 2;
      *reinterpret_cast<int*>(yrow + d0) = pk;
    }
  }
}

// ---------------------------------------------------------------- launcher
extern "C" void kernel_launch(void* const* d_in, const int* in_sizes, int n_in,
                              void* d_out, int out_size, void* d_ws, size_t ws_size,
                              hipStream_t stream) {
  const float* x = (const float*)d_in[0];       // [4,2048,1024]
  const float* wqkv = (const float*)d_in[1];    // [1024,3072]
  const float* wproj = (const float*)d_in[2];   // [1024,1024]
  float* out = (float*)d_out;                   // [4,2048,1024] fp32

  char* ws = (char*)d_ws;
  u16* xb     = (u16*)(ws);                 // 16.78 MB  [8192][1024] bf16
  u16* wqkvT  = (u16*)(ws + 16777216);      //  6.29 MB  [3072][1024] bf16
  u16* wprojT = (u16*)(ws + 23068672);      //  2.10 MB  [1024][1024] bf16
  u16* qw     = (u16*)(ws + 25165824);      // 16.78 MB  [64][2048][64]
  u16* kw     = (u16*)(ws + 41943040);      // 16.78 MB  [64][2048][64]
  u16* vtw    = (u16*)(ws + 58720256);      // 16.78 MB  [64][64][2048]
  u16* yw     = (u16*)(ws + 75497472);      // 16.78 MB  [8192][1024]
  (void)in_sizes; (void)n_in; (void)out_size; (void)ws_size;

  cast_x_kernel<<<8192, 256, 0, stream>>>(x, xb);
  transpose_cast<<<dim3(48, 16), 256, 0, stream>>>(wqkv, wqkvT, 1024, 3072);
  transpose_cast<<<dim3(16, 16), 256, 0, stream>>>(wproj, wprojT, 1024, 1024);
  gemmp<0><<<dim3(24, 32), 512, 0, stream>>>(xb, wqkvT, nullptr, 3072, qw, kw, vtw);
  attn_fwd<<<dim3(64, 16), 256, 0, stream>>>(qw, kw, vtw, yw);
  gemmp<1><<<dim3(8, 32), 512, 0, stream>>>(yw, wprojT, out, 1024,
                                            nullptr, nullptr, nullptr);
}